// Round 7
// baseline (643.945 us; speedup 1.0000x reference)
//
#include <hip/hip_runtime.h>
#include <hip/hip_bf16.h>
#include <hip/hip_fp16.h>
#include <math.h>

#define NPROJ 1024
#define NHEADS 4
#define NHID 256
#define NGRAPH 64

typedef _Float16 half8 __attribute__((ext_vector_type(8)));
typedef _Float16 half4v __attribute__((ext_vector_type(4)));
typedef float floatx4 __attribute__((ext_vector_type(4)));

#define GLD_LDS16(g, l)                                                        \
  __builtin_amdgcn_global_load_lds(                                            \
      (const __attribute__((address_space(1))) unsigned int*)(g),              \
      (__attribute__((address_space(3))) unsigned int*)(l), 16, 0, 0)

// ============================================================
// Single-product f16 MFMA GEMM:  C = A @ BT^T   (K fixed = 1024)
// A: M x 1024 f16 (hi of fp32).  B TRANSPOSED: Nc x 1024 f16 (hi of fp32).
// (residual B-lo term ~1.4e-4 rms on C -- same scale as other f16 paths.)
// 128x128 tile, BK=64, 4 waves (2x2), wave 64x64, 16x16x32 MFMA.
// LDS = 2 x 16KB = 32KB -> 4 blocks/CU; grid 640 fits one residency round.
// Single-buffer overlap: frags->regs, barrier, STAGE(t+1) under MFMAs.
// XOR-swizzled LDS via pre-swizzled global source.
// XCD-chunked grid: each XCD owns mpad8 contiguous row-slabs, bx fastest.
// ============================================================
template<int ACT, int OUT>  // ACT: 0 none, 1 tanh; OUT: 0 f32, 1 split pair, 2 f16
__global__ __launch_bounds__(256, 4) void gemm_mfma(
    const _Float16* __restrict__ A, const _Float16* __restrict__ BT,
    const float* __restrict__ bias, float* __restrict__ Cf,
    _Float16* __restrict__ Ch, _Float16* __restrict__ Cl,
    int M, int Nc, int lgn, int mpad8)
{
  __shared__ __align__(16) _Float16 ldsA[128 * 64];
  __shared__ __align__(16) _Float16 ldsB[128 * 64];

  const int id  = blockIdx.x;
  const int xcd = id & 7;
  const int kk  = id >> 3;
  const int bx  = kk & ((1 << lgn) - 1);
  const int by  = xcd * mpad8 + (kk >> lgn);
  const int m0  = by * 128, n0 = bx * 128;
  if (m0 >= M) return;

  const int tid  = threadIdx.x;
  const int lane = tid & 63;
  const int wave = tid >> 6;
  const int wm = wave >> 1, wn = wave & 1;

  // staging: chunk ci = r*256 + tid covers LDS bytes ci*16.
  // row = ci>>3, phys chunk-in-row = ci&7, stored logical k-chunk =
  // (ci&7) ^ (row&7)  (XOR swizzle involution)
  const int srow = tid >> 3;                              // + r*32
  const int kc8  = (((tid & 7) ^ ((tid >> 3) & 7)) << 3); // logical k elems
  const int wb16 = (tid & ~63) * 16;                      // wave-uniform base

  floatx4 acc[4][4] = {};

  const int l15 = lane & 15;
  const int swz = (l15 & 7) << 4;
  const int kbyte0 = (lane >> 4) * 16;

  auto STAGE = [&](int t) {
    const int k0 = t << 6;
#pragma unroll
    for (int r = 0; r < 4; ++r) {
      int rowA = m0 + r * 32 + srow;
      rowA = rowA < M ? rowA : (M - 1);
      GLD_LDS16(A + (size_t)rowA * 1024 + k0 + kc8,
                (char*)ldsA + r * 4096 + wb16);
      GLD_LDS16(BT + (size_t)(n0 + r * 32 + srow) * 1024 + k0 + kc8,
                (char*)ldsB + r * 4096 + wb16);
    }
  };

  STAGE(0);
  __syncthreads();

  for (int t = 0; t < 16; ++t) {
    // ---- ks=0 fragments -> regs ----
    const int koff0 = kbyte0 ^ swz;
    half8 a0[4], b0[4];
#pragma unroll
    for (int i = 0; i < 4; ++i)
      a0[i] = *(const half8*)((const char*)ldsA +
                              (wm * 64 + i * 16 + l15) * 128 + koff0);
#pragma unroll
    for (int j = 0; j < 4; ++j)
      b0[j] = *(const half8*)((const char*)ldsB +
                              (wn * 64 + j * 16 + l15) * 128 + koff0);
    // ---- 16 MFMAs on ks=0 ----
#pragma unroll
    for (int i = 0; i < 4; ++i)
#pragma unroll
      for (int j = 0; j < 4; ++j)
        acc[i][j] = __builtin_amdgcn_mfma_f32_16x16x32_f16(a0[i], b0[j],
                                                           acc[i][j], 0, 0, 0);

    // ---- ks=1 fragments -> regs ----
    const int koff1 = (64 + kbyte0) ^ swz;
    half8 a1[4], b1[4];
#pragma unroll
    for (int i = 0; i < 4; ++i)
      a1[i] = *(const half8*)((const char*)ldsA +
                              (wm * 64 + i * 16 + l15) * 128 + koff1);
#pragma unroll
    for (int j = 0; j < 4; ++j)
      b1[j] = *(const half8*)((const char*)ldsB +
                              (wn * 64 + j * 16 + l15) * 128 + koff1);
    __syncthreads();            // all LDS reads of tile t complete (regs held)
    if (t < 15) STAGE(t + 1);   // overwrite LDS under the MFMAs below

    // ---- 16 MFMAs on ks=1 ----
#pragma unroll
    for (int i = 0; i < 4; ++i)
#pragma unroll
      for (int j = 0; j < 4; ++j)
        acc[i][j] = __builtin_amdgcn_mfma_f32_16x16x32_f16(a1[i], b1[j],
                                                           acc[i][j], 0, 0, 0);

    if (t < 15) __syncthreads();  // vmcnt drain (mostly hidden by MFMAs)
  }

  // epilogue: C[row = (lane>>4)*4 + reg, col = lane&15] per 16x16 frag
  const int rbase = (lane >> 4) * 4;
#pragma unroll
  for (int j = 0; j < 4; ++j) {
    const int col = n0 + wn * 64 + j * 16 + l15;
    const float bv = bias ? bias[col] : 0.f;
#pragma unroll
    for (int i = 0; i < 4; ++i) {
      const int gm0 = m0 + wm * 64 + i * 16 + rbase;
#pragma unroll
      for (int r = 0; r < 4; ++r) {
        const int gm = gm0 + r;
        if (gm >= M) continue;
        float v = acc[i][j][r] + bv;
        if (ACT == 1) v = tanhf(v);
        if (OUT == 1) {
          _Float16 hh = (_Float16)v;
          Ch[(size_t)gm * Nc + col] = hh;
          Cl[(size_t)gm * Nc + col] = (_Float16)(v - (float)hh);
        } else if (OUT == 2) {
          Ch[(size_t)gm * Nc + col] = (_Float16)v;
        } else {
          Cf[(size_t)gm * Nc + col] = v;
        }
      }
    }
  }
}

// ============================================================
// converters
// ============================================================
__global__ void k_tof16(const float* __restrict__ in, _Float16* __restrict__ h,
                        int L8) {
  int i = blockIdx.x * 256 + threadIdx.x;
  if (i >= L8) return;
  const float4* p = (const float4*)(in + (size_t)i * 8);
  float4 v0 = p[0], v1 = p[1];
  float vv[8] = {v0.x, v0.y, v0.z, v0.w, v1.x, v1.y, v1.z, v1.w};
  half8 hv;
#pragma unroll
  for (int j = 0; j < 8; ++j) hv[j] = (_Float16)vv[j];
  *(half8*)(h + (size_t)i * 8) = hv;
}

// W (K x Nc) fp32 -> transposed (Nc x K) f16
__global__ __launch_bounds__(256) void k_transT(const float* __restrict__ in,
                                                _Float16* __restrict__ hT,
                                                int K, int Nc) {
  __shared__ float t[32][33];
  const int tx = threadIdx.x & 31, ty = threadIdx.x >> 5;
  const int c0 = blockIdx.x * 32, k0 = blockIdx.y * 32;
#pragma unroll
  for (int r = 0; r < 4; ++r)
    t[ty + 8 * r][tx] = in[(size_t)(k0 + ty + 8 * r) * Nc + c0 + tx];
  __syncthreads();
#pragma unroll
  for (int r = 0; r < 4; ++r) {
    float v = t[tx][ty + 8 * r];
    int oc = c0 + ty + 8 * r;
    hT[(size_t)oc * K + k0 + tx] = (_Float16)v;
  }
}

// ============================================================
// CSR-by-dst construction (recomputed every call; no caching)
// ============================================================
__global__ void k_init_counts(int* cnt, int n) {
  int i = blockIdx.x * 256 + threadIdx.x;
  if (i < n) cnt[i] = 1;  // self-loop pre-counted
}

__global__ void k_count(const int* __restrict__ dst, int* cnt, int e) {
  int i = blockIdx.x * 256 + threadIdx.x;
  if (i < e) atomicAdd(&cnt[dst[i]], 1);
}

__global__ __launch_bounds__(1024) void k_scan(const int* __restrict__ cnt,
                                               int* __restrict__ rowstart,
                                               int* __restrict__ cursor, int n) {
  __shared__ int buf[1024];
  __shared__ int carry;
  int t = threadIdx.x;
  if (t == 0) carry = 0;
  __syncthreads();
  for (int base = 0; base < n; base += 1024) {
    int x = (base + t < n) ? cnt[base + t] : 0;
    buf[t] = x;
    __syncthreads();
    for (int off = 1; off < 1024; off <<= 1) {
      int v = (t >= off) ? buf[t - off] : 0;
      __syncthreads();
      buf[t] += v;
      __syncthreads();
    }
    int c0 = carry;
    int excl = buf[t] - x + c0;
    if (base + t < n) { rowstart[base + t] = excl; cursor[base + t] = excl; }
    __syncthreads();
    if (t == 0) carry = c0 + buf[1023];
    __syncthreads();
  }
  if (t == 0) rowstart[n] = carry;
}

__global__ void k_fill(const int* __restrict__ src, const int* __restrict__ dst,
                       int* cursor, int* __restrict__ col, int e) {
  int i = blockIdx.x * 256 + threadIdx.x;
  if (i < e) {
    int p = atomicAdd(&cursor[dst[i]], 1);
    col[p] = src[i];
  }
}

__global__ void k_fill_self(int* cursor, int* __restrict__ col, int n) {
  int i = blockIdx.x * 256 + threadIdx.x;
  if (i < n) {
    int p = atomicAdd(&cursor[i], 1);
    col[p] = i;
  }
}

// ============================================================
// per-node attention logits (f16 h): one wave per head
// ============================================================
__global__ __launch_bounds__(256) void k_alpha(
    const _Float16* __restrict__ h, const float* __restrict__ a_src,
    const float* __restrict__ a_dst, float* __restrict__ as_out,
    float* __restrict__ ad_out) {
  int n = blockIdx.x, t = threadIdx.x;
  const int wv = t >> 6, ln = t & 63;     // wave = head
  const int cb = wv * 256 + 4 * ln;
  half4v v = *(const half4v*)(h + (size_t)n * NPROJ + cb);
  float4 s4 = *(const float4*)(a_src + cb);
  float4 d4 = *(const float4*)(a_dst + cb);
  float vv[4] = {(float)v[0], (float)v[1], (float)v[2], (float)v[3]};
  float ss = vv[0] * s4.x + vv[1] * s4.y + vv[2] * s4.z + vv[3] * s4.w;
  float sd = vv[0] * d4.x + vv[1] * d4.y + vv[2] * d4.z + vv[3] * d4.w;
#pragma unroll
  for (int off = 32; off > 0; off >>= 1) {
    ss += __shfl_down(ss, off);
    sd += __shfl_down(sd, off);
  }
  if (ln == 0) {
    as_out[n * 4 + wv] = ss;
    ad_out[n * 4 + wv] = sd;
  }
}

// ============================================================
// fused segment-softmax + aggregation (f16 h, 4 edge-groups)
//        + bias + ELU + residual + LayerNorm
// 512 threads: group g = t>>7 handles edges e%4==g, 128 col-threads x 8 f16
// ============================================================
__device__ __forceinline__ float lrelu02(float x) {
  return x > 0.f ? x : 0.2f * x;
}

__global__ __launch_bounds__(512) void k_aggregate_ln(
    const _Float16* __restrict__ h, const float* __restrict__ as_,
    const float* __restrict__ ad_, const int* __restrict__ rowstart,
    const int* __restrict__ col, const float* __restrict__ bias,
    const float* __restrict__ gamma, const float* __restrict__ beta,
    _Float16* __restrict__ xh, _Float16* __restrict__ xl) {
  __shared__ float redm[4][512];
  __shared__ float wts[512][5];    // pad 5 -> conflict-free writes
  __shared__ int scol[512];
  __shared__ float combo[3][128][9];  // pad 9 -> conflict-free
  __shared__ float Mh[4], Sh[4];
  __shared__ float mu_s, rstd_s;

  int n = blockIdx.x, t = threadIdx.x;
  int rs = rowstart[n], re = rowstart[n + 1];
  float4 ad4 = *(const float4*)(ad_ + n * 4);
  float adn[4] = {ad4.x, ad4.y, ad4.z, ad4.w};

  // pass 1: per-head max
  float mx[4] = {-1e30f, -1e30f, -1e30f, -1e30f};
  for (int e = rs + t; e < re; e += 512) {
    int s = col[e];
    float4 a4 = *(const float4*)(as_ + (size_t)s * 4);
    float av[4] = {a4.x, a4.y, a4.z, a4.w};
#pragma unroll
    for (int j = 0; j < 4; ++j)
      mx[j] = fmaxf(mx[j], lrelu02(av[j] + adn[j]));
  }
#pragma unroll
  for (int j = 0; j < 4; ++j) redm[j][t] = mx[j];
  __syncthreads();
  for (int s = 256; s > 0; s >>= 1) {
    if (t < s)
#pragma unroll
      for (int j = 0; j < 4; ++j)
        redm[j][t] = fmaxf(redm[j][t], redm[j][t + s]);
    __syncthreads();
  }
  if (t < 4) Mh[t] = redm[t][0];
  __syncthreads();
  float M_[4];
#pragma unroll
  for (int j = 0; j < 4; ++j) M_[j] = Mh[j];
  __syncthreads();

  // pass 2: sum of exp
  float sm[4] = {0.f, 0.f, 0.f, 0.f};
  for (int e = rs + t; e < re; e += 512) {
    int s = col[e];
    float4 a4 = *(const float4*)(as_ + (size_t)s * 4);
    float av[4] = {a4.x, a4.y, a4.z, a4.w};
#pragma unroll
    for (int j = 0; j < 4; ++j)
      sm[j] += expf(lrelu02(av[j] + adn[j]) - M_[j]);
  }
#pragma unroll
  for (int j = 0; j < 4; ++j) redm[j][t] = sm[j];
  __syncthreads();
  for (int s = 256; s > 0; s >>= 1) {
    if (t < s)
#pragma unroll
      for (int j = 0; j < 4; ++j) redm[j][t] += redm[j][t + s];
    __syncthreads();
  }
  if (t < 4) Sh[t] = redm[t][0];
  __syncthreads();
  float S_[4];
#pragma unroll
  for (int j = 0; j < 4; ++j) S_[j] = Sh[j] + 1e-16f;
  __syncthreads();

  // pass 3: weighted aggregation; 4 edge-groups, 8 f16 cols per thread
  const int g = t >> 7, c = t & 127;
  const int hd = c >> 5;
  float acc8[8] = {};
  for (int c0 = rs; c0 < re; c0 += 512) {
    int cnt = min(512, re - c0);
    if (t < cnt) {
      int s = col[c0 + t];
      scol[t] = s;
      float4 a4 = *(const float4*)(as_ + (size_t)s * 4);
      float av[4] = {a4.x, a4.y, a4.z, a4.w};
#pragma unroll
      for (int j = 0; j < 4; ++j)
        wts[t][j] = expf(lrelu02(av[j] + adn[j]) - M_[j]) / S_[j];
    }
    __syncthreads();
    for (int e = g; e < cnt; e += 4) {
      float w = wts[e][hd];
      half8 hv = *(const half8*)(h + (size_t)scol[e] * NPROJ + 8 * c);
#pragma unroll
      for (int j = 0; j < 8; ++j) acc8[j] = fmaf(w, (float)hv[j], acc8[j]);
    }
    __syncthreads();
  }
  // combine the four edge-groups
  if (g) {
#pragma unroll
    for (int j = 0; j < 8; ++j) combo[g - 1][c][j] = acc8[j];
  }
  __syncthreads();
  if (g == 0) {
#pragma unroll
    for (int q = 0; q < 3; ++q)
#pragma unroll
      for (int j = 0; j < 8; ++j) acc8[j] += combo[q][c][j];
  }

  // epilogue: bias, ELU, residual, LayerNorm (g==0 threads own cols 8c..8c+7)
  const size_t base = (size_t)n * NPROJ + 8 * c;
  float v[8];
  float sum = 0.f, sumsq = 0.f;
  if (g == 0) {
    float4 b0 = *(const float4*)(bias + 8 * c);
    float4 b1 = *(const float4*)(bias + 8 * c + 4);
    float bvv[8] = {b0.x, b0.y, b0.z, b0.w, b1.x, b1.y, b1.z, b1.w};
    half8 xhv = *(const half8*)(xh + base);
    half8 xlv = *(const half8*)(xl + base);
#pragma unroll
    for (int j = 0; j < 8; ++j) {
      float u = acc8[j] + bvv[j];
      u = u > 0.f ? u : expm1f(u);
      u += (float)xhv[j] + (float)xlv[j];
      v[j] = u;
      sum += u;
      sumsq += u * u;
    }
  }
  redm[0][t] = g == 0 ? sum : 0.f;
  redm[1][t] = g == 0 ? sumsq : 0.f;
  __syncthreads();
  for (int s = 64; s > 0; s >>= 1) {
    if (t < s) {
      redm[0][t] += redm[0][t + s];
      redm[1][t] += redm[1][t + s];
    }
    __syncthreads();
  }
  if (t == 0) {
    float mu = redm[0][0] * (1.f / 1024.f);
    float var = redm[1][0] * (1.f / 1024.f) - mu * mu;
    mu_s = mu;
    rstd_s = rsqrtf(var + 1e-5f);
  }
  __syncthreads();
  if (g == 0) {
    float mu = mu_s, rstd = rstd_s;
    float4 g0 = *(const float4*)(gamma + 8 * c);
    float4 g1 = *(const float4*)(gamma + 8 * c + 4);
    float4 e0 = *(const float4*)(beta + 8 * c);
    float4 e1 = *(const float4*)(beta + 8 * c + 4);
    float gvv[8] = {g0.x, g0.y, g0.z, g0.w, g1.x, g1.y, g1.z, g1.w};
    float bev[8] = {e0.x, e0.y, e0.z, e0.w, e1.x, e1.y, e1.z, e1.w};
    half8 oh, ol;
#pragma unroll
    for (int j = 0; j < 8; ++j) {
      float y = (v[j] - mu) * rstd * gvv[j] + bev[j];
      _Float16 hh = (_Float16)y;
      oh[j] = hh;
      ol[j] = (_Float16)(y - (float)hh);
    }
    *(half8*)(xh + base) = oh;
    *(half8*)(xl + base) = ol;
  }
}

// ============================================================
// pooling + classifier
// ============================================================
__global__ void k_scores(const float* __restrict__ tb,
                         const float* __restrict__ W2,
                         const float* __restrict__ b2,
                         float* __restrict__ scores, int N) {
  int n = blockIdx.x, lane = threadIdx.x;
  float s = 0.f;
  for (int k = lane; k < 512; k += 64) s = fmaf(tb[(size_t)n * 512 + k], W2[k], s);
  for (int off = 32; off > 0; off >>= 1) s += __shfl_down(s, off);
  if (lane == 0) scores[n] = s + b2[0];
}

__global__ void k_grange_init(int* gstart, int* gend, int N) {
  int g = threadIdx.x;
  if (g < NGRAPH) { gstart[g] = N; gend[g] = 0; }
}

__global__ void k_grange_mark(const int* __restrict__ batch, int* gstart,
                              int* gend, int N) {
  int n = blockIdx.x * 256 + threadIdx.x;
  if (n >= N) return;
  int b = batch[n];
  if (n == 0 || batch[n - 1] != b) gstart[b] = n;
  if (n == N - 1 || batch[n + 1] != b) gend[b] = n + 1;
}

__global__ __launch_bounds__(256) void k_pool(
    const float* __restrict__ scores, const _Float16* __restrict__ xh,
    const _Float16* __restrict__ xl, const int* __restrict__ gstart,
    const int* __restrict__ gend, float* __restrict__ pooled) {
  __shared__ float red[256];
  __shared__ float wt[256];
  __shared__ float m_s, s_s;
  int g = blockIdx.x, t = threadIdx.x;
  int rs = gstart[g], re = gend[g];

  float mx = -1e30f;
  for (int i = rs + t; i < re; i += 256) mx = fmaxf(mx, scores[i]);
  red[t] = mx;
  __syncthreads();
  for (int s = 128; s > 0; s >>= 1) {
    if (t < s) red[t] = fmaxf(red[t], red[t + s]);
    __syncthreads();
  }
  if (t == 0) m_s = red[0];
  __syncthreads();
  float m = m_s;

  float sm = 0.f;
  for (int i = rs + t; i < re; i += 256) sm += expf(scores[i] - m);
  red[t] = sm;
  __syncthreads();
  for (int s = 128; s > 0; s >>= 1) {
    if (t < s) red[t] += red[t + s];
    __syncthreads();
  }
  if (t == 0) s_s = red[0] + 1e-16f;
  __syncthreads();
  float sden = s_s;

  float acc[4] = {0.f, 0.f, 0.f, 0.f};
  for (int c0 = rs; c0 < re; c0 += 256) {
    int cnt = min(256, re - c0);
    if (t < cnt) wt[t] = expf(scores[c0 + t] - m) / sden;
    __syncthreads();
    for (int e = 0; e < cnt; ++e) {
      float w = wt[e];
      size_t base = (size_t)(c0 + e) * NPROJ + 4 * t;
      half4v hv = *(const half4v*)(xh + base);
      half4v lv = *(const half4v*)(xl + base);
#pragma unroll
      for (int j = 0; j < 4; ++j)
        acc[j] = fmaf(w, (float)hv[j] + (float)lv[j], acc[j]);
    }
    __syncthreads();
  }
#pragma unroll
  for (int j = 0; j < 4; ++j) pooled[(size_t)g * NPROJ + 4 * t + j] = acc[j];
}

__global__ __launch_bounds__(256) void k_cls1(const float* __restrict__ pooled,
                                              const float* __restrict__ W1,
                                              const float* __restrict__ b1,
                                              float* __restrict__ hid) {
  __shared__ float p[1024];
  int g = blockIdx.y;
  int colc = blockIdx.x * 256 + threadIdx.x;
  for (int k = threadIdx.x; k < 1024; k += 256) p[k] = pooled[(size_t)g * 1024 + k];
  __syncthreads();
  float s = 0.f;
  for (int k = 0; k < 1024; ++k) s = fmaf(p[k], W1[(size_t)k * 512 + colc], s);
  s += b1[colc];
  s = 0.5f * s * (1.f + erff(s * 0.70710678118654752f));
  hid[(size_t)g * 512 + colc] = s;
}

__global__ void k_cls2(const float* __restrict__ hid,
                       const float* __restrict__ W2,
                       const float* __restrict__ b2, float* __restrict__ out) {
  int o = blockIdx.x, g = blockIdx.y, lane = threadIdx.x;
  float s = 0.f;
  for (int k = lane; k < 512; k += 64) s = fmaf(hid[(size_t)g * 512 + k], W2[k * 14 + o], s);
  for (int off = 32; off > 0; off >>= 1) s += __shfl_down(s, off);
  if (lane == 0) out[g * 14 + o] = s + b2[o];
}

// ============================================================
extern "C" void kernel_launch(void* const* d_in, const int* in_sizes, int n_in,
                              void* d_out, int out_size, void* d_ws, size_t ws_size,
                              hipStream_t stream) {
  const float* x_in   = (const float*)d_in[0];
  const int*   eidx   = (const int*)d_in[1];
  const int*   batch  = (const int*)d_in[2];
  const float* proj_W = (const float*)d_in[3];
  const float* proj_b = (const float*)d_in[4];
  const float* gat_W  = (const float*)d_in[5];
  const float* a_src  = (const float*)d_in[6];
  const float* a_dst  = (const float*)d_in[7];
  const float* gat_b  = (const float*)d_in[8];
  const float* gamma  = (const float*)d_in[9];
  const float* beta   = (const float*)d_in[10];
  const float* pW1    = (const float*)d_in[11];
  const float* pb1    = (const float*)d_in[12];
  const float* pW2    = (const float*)d_in[13];
  const float* pb2    = (const float*)d_in[14];
  const float* cW1    = (const float*)d_in[15];
  const float* cb1    = (const float*)d_in[16];
  const float* cW2    = (const float*)d_in[17];
  const float* cb2    = (const float*)d_in[18];
  float* out = (float*)d_out;

  const int N = in_sizes[0] / NPROJ;  // 10000
  const int E = in_sizes[1] / 2;      // 160000
  const int Etot = E + N;

  char* ws = (char*)d_ws;
  size_t off = 0;
  auto alloc = [&](size_t bytes) -> void* {
    void* p = ws + off;
    off = (off + bytes + 255) & ~(size_t)255;
    return p;
  };
  _Float16* xh   = (_Float16*)alloc((size_t)N * NPROJ * 2);
  _Float16* xl   = (_Float16*)alloc((size_t)N * NPROJ * 2);
  _Float16* hf   = (_Float16*)alloc((size_t)N * NPROJ * 2);   // f16 h
  float*    hb   = (float*)alloc((size_t)N * NPROJ * 4);      // in-f16 / tb
  _Float16* pjh  = (_Float16*)alloc((size_t)NPROJ * NPROJ * 2);
  _Float16* gwh  = (_Float16*)alloc((size_t)3 * NPROJ * NPROJ * 2);
  _Float16* pwh  = (_Float16*)alloc((size_t)512 * NPROJ * 2);
  float* asb     = (float*)alloc((size_t)N * 4 * 4);
  float* adb     = (float*)alloc((size_t)N * 4 * 4);
  int*   cnt     = (int*)alloc((size_t)N * 4);
  int*   rowst   = (int*)alloc((size_t)(N + 1) * 4);
  int*   cursor  = (int*)alloc((size_t)N * 4);
  int*   ccol    = (int*)alloc((size_t)Etot * 4);
  float* scores  = (float*)alloc((size_t)N * 4);
  int*   gstart  = (int*)alloc(NGRAPH * 4);
  int*   gend    = (int*)alloc(NGRAPH * 4);
  float* pooled  = (float*)alloc((size_t)NGRAPH * NPROJ * 4);
  float* hid     = (float*)alloc((size_t)NGRAPH * 512 * 4);

  const int* esrc = eidx;
  const int* edst = eidx + E;

  // ---- CSR by dst ----
  k_init_counts<<<(N + 255) / 256, 256, 0, stream>>>(cnt, N);
  k_count<<<(E + 255) / 256, 256, 0, stream>>>(edst, cnt, E);
  k_scan<<<1, 1024, 0, stream>>>(cnt, rowst, cursor, N);
  k_fill<<<(E + 255) / 256, 256, 0, stream>>>(esrc, edst, cursor, ccol, E);
  k_fill_self<<<(N + 255) / 256, 256, 0, stream>>>(cursor, ccol, N);

  // ---- weight transposes (f16 hi) ----
  k_transT<<<dim3(32, 32), 256, 0, stream>>>(proj_W, pjh, NPROJ, NPROJ);
  for (int i = 0; i < 3; ++i)
    k_transT<<<dim3(32, 32), 256, 0, stream>>>(gat_W + (size_t)i * NPROJ * NPROJ,
                                               gwh + (size_t)i * NPROJ * NPROJ,
                                               NPROJ, NPROJ);
  k_transT<<<dim3(16, 32), 256, 0, stream>>>(pW1, pwh, NPROJ, 512);

  // ---- input f16 (scratch inside hb) + projection ----
  _Float16* inh = (_Float16*)hb;
  k_tof16<<<((N * NPROJ / 8) + 255) / 256, 256, 0, stream>>>(x_in, inh,
                                                             N * NPROJ / 8);
  const int MB = (N + 127) / 128;       // 79
  const int mpad8 = (MB + 7) / 8;       // 10
  const dim3 grid8(8 * mpad8 * 8);      // Nc=1024: lgn=3
  const dim3 grid4(4 * mpad8 * 8);      // Nc=512:  lgn=2
  gemm_mfma<0, 1><<<grid8, 256, 0, stream>>>(
      inh, pjh, proj_b, nullptr, xh, xl, N, NPROJ, 3, mpad8);

  // ---- 3 GAT layers ----
  for (int i = 0; i < 3; ++i) {
    gemm_mfma<0, 2><<<grid8, 256, 0, stream>>>(
        xh, gwh + (size_t)i * NPROJ * NPROJ,
        nullptr, nullptr, hf, nullptr, N, NPROJ, 3, mpad8);
    k_alpha<<<N, 256, 0, stream>>>(hf, a_src + i * NPROJ, a_dst + i * NPROJ, asb, adb);
    k_aggregate_ln<<<N, 512, 0, stream>>>(hf, asb, adb, rowst, ccol,
                                          gat_b + i * NPROJ, gamma + i * NPROJ,
                                          beta + i * NPROJ, xh, xl);
  }

  // ---- attention pooling ----
  float* tb = hb;  // N x 512 f32
  gemm_mfma<1, 0><<<grid4, 256, 0, stream>>>(
      xh, pwh, pb1, tb, nullptr, nullptr, N, 512, 2, mpad8);
  k_scores<<<N, 64, 0, stream>>>(tb, pW2, pb2, scores, N);
  k_grange_init<<<1, 64, 0, stream>>>(gstart, gend, N);
  k_grange_mark<<<(N + 255) / 256, 256, 0, stream>>>(batch, gstart, gend, N);
  k_pool<<<NGRAPH, 256, 0, stream>>>(scores, xh, xl, gstart, gend, pooled);

  // ---- classifier ----
  k_cls1<<<dim3(2, NGRAPH), 256, 0, stream>>>(pooled, cW1, cb1, hid);
  k_cls2<<<dim3(14, NGRAPH), 64, 0, stream>>>(hid, cW2, cb2, out);
}

// Round 8
// 528.961 us; speedup vs baseline: 1.2174x; 1.2174x over previous
//
#include <hip/hip_runtime.h>
#include <hip/hip_bf16.h>
#include <hip/hip_fp16.h>
#include <math.h>

#define NPROJ 1024
#define NHEADS 4
#define NHID 256
#define NGRAPH 64

typedef _Float16 half8 __attribute__((ext_vector_type(8)));
typedef _Float16 half4v __attribute__((ext_vector_type(4)));
typedef float floatx4 __attribute__((ext_vector_type(4)));

#define GLD_LDS16(g, l)                                                        \
  __builtin_amdgcn_global_load_lds(                                            \
      (const __attribute__((address_space(1))) unsigned int*)(g),              \
      (__attribute__((address_space(3))) unsigned int*)(l), 16, 0, 0)

// ============================================================
// Single-product f16 MFMA GEMM:  C = A @ BT^T   (K fixed = 1024)
// A: M x 1024 f16 (hi of fp32).  B TRANSPOSED: Nc x 1024 f16 (hi of fp32).
// 128x128 tile, BK=64, 4 waves (2x2), wave 64x64, 16x16x32 MFMA.
// LDS = 2 x 16KB = 32KB -> 4 blocks/CU; grid 640 fits one residency round.
// Single-buffer overlap: frags->regs, barrier, STAGE(t+1) under MFMAs.
// XOR-swizzled LDS via pre-swizzled global source.
// XCD-chunked grid: each XCD owns mpad8 contiguous row-slabs, bx fastest.
// ============================================================
template<int ACT, int OUT>  // ACT: 0 none, 1 tanh; OUT: 0 f32, 1 split pair, 2 f16
__global__ __launch_bounds__(256, 4) void gemm_mfma(
    const _Float16* __restrict__ A, const _Float16* __restrict__ BT,
    const float* __restrict__ bias, float* __restrict__ Cf,
    _Float16* __restrict__ Ch, _Float16* __restrict__ Cl,
    int M, int Nc, int lgn, int mpad8)
{
  __shared__ __align__(16) _Float16 ldsA[128 * 64];
  __shared__ __align__(16) _Float16 ldsB[128 * 64];

  const int id  = blockIdx.x;
  const int xcd = id & 7;
  const int kk  = id >> 3;
  const int bx  = kk & ((1 << lgn) - 1);
  const int by  = xcd * mpad8 + (kk >> lgn);
  const int m0  = by * 128, n0 = bx * 128;
  if (m0 >= M) return;

  const int tid  = threadIdx.x;
  const int lane = tid & 63;
  const int wave = tid >> 6;
  const int wm = wave >> 1, wn = wave & 1;

  const int srow = tid >> 3;                              // + r*32
  const int kc8  = (((tid & 7) ^ ((tid >> 3) & 7)) << 3); // logical k elems
  const int wb16 = (tid & ~63) * 16;                      // wave-uniform base

  floatx4 acc[4][4] = {};

  const int l15 = lane & 15;
  const int swz = (l15 & 7) << 4;
  const int kbyte0 = (lane >> 4) * 16;

  auto STAGE = [&](int t) {
    const int k0 = t << 6;
#pragma unroll
    for (int r = 0; r < 4; ++r) {
      int rowA = m0 + r * 32 + srow;
      rowA = rowA < M ? rowA : (M - 1);
      GLD_LDS16(A + (size_t)rowA * 1024 + k0 + kc8,
                (char*)ldsA + r * 4096 + wb16);
      GLD_LDS16(BT + (size_t)(n0 + r * 32 + srow) * 1024 + k0 + kc8,
                (char*)ldsB + r * 4096 + wb16);
    }
  };

  STAGE(0);
  __syncthreads();

  for (int t = 0; t < 16; ++t) {
    const int koff0 = kbyte0 ^ swz;
    half8 a0[4], b0[4];
#pragma unroll
    for (int i = 0; i < 4; ++i)
      a0[i] = *(const half8*)((const char*)ldsA +
                              (wm * 64 + i * 16 + l15) * 128 + koff0);
#pragma unroll
    for (int j = 0; j < 4; ++j)
      b0[j] = *(const half8*)((const char*)ldsB +
                              (wn * 64 + j * 16 + l15) * 128 + koff0);
#pragma unroll
    for (int i = 0; i < 4; ++i)
#pragma unroll
      for (int j = 0; j < 4; ++j)
        acc[i][j] = __builtin_amdgcn_mfma_f32_16x16x32_f16(a0[i], b0[j],
                                                           acc[i][j], 0, 0, 0);

    const int koff1 = (64 + kbyte0) ^ swz;
    half8 a1[4], b1[4];
#pragma unroll
    for (int i = 0; i < 4; ++i)
      a1[i] = *(const half8*)((const char*)ldsA +
                              (wm * 64 + i * 16 + l15) * 128 + koff1);
#pragma unroll
    for (int j = 0; j < 4; ++j)
      b1[j] = *(const half8*)((const char*)ldsB +
                              (wn * 64 + j * 16 + l15) * 128 + koff1);
    __syncthreads();            // all LDS reads of tile t complete (regs held)
    if (t < 15) STAGE(t + 1);   // overwrite LDS under the MFMAs below

#pragma unroll
    for (int i = 0; i < 4; ++i)
#pragma unroll
      for (int j = 0; j < 4; ++j)
        acc[i][j] = __builtin_amdgcn_mfma_f32_16x16x32_f16(a1[i], b1[j],
                                                           acc[i][j], 0, 0, 0);

    if (t < 15) __syncthreads();  // vmcnt drain (mostly hidden by MFMAs)
  }

  // epilogue: C[row = (lane>>4)*4 + reg, col = lane&15] per 16x16 frag
  const int rbase = (lane >> 4) * 4;
#pragma unroll
  for (int j = 0; j < 4; ++j) {
    const int col = n0 + wn * 64 + j * 16 + l15;
    const float bv = bias ? bias[col] : 0.f;
#pragma unroll
    for (int i = 0; i < 4; ++i) {
      const int gm0 = m0 + wm * 64 + i * 16 + rbase;
#pragma unroll
      for (int r = 0; r < 4; ++r) {
        const int gm = gm0 + r;
        if (gm >= M) continue;
        float v = acc[i][j][r] + bv;
        if (ACT == 1) v = tanhf(v);
        if (OUT == 1) {
          _Float16 hh = (_Float16)v;
          Ch[(size_t)gm * Nc + col] = hh;
          Cl[(size_t)gm * Nc + col] = (_Float16)(v - (float)hh);
        } else if (OUT == 2) {
          Ch[(size_t)gm * Nc + col] = (_Float16)v;
        } else {
          Cf[(size_t)gm * Nc + col] = v;
        }
      }
    }
  }
}

// ============================================================
// converters
// ============================================================
__global__ void k_tof16(const float* __restrict__ in, _Float16* __restrict__ h,
                        int L8) {
  int i = blockIdx.x * 256 + threadIdx.x;
  if (i >= L8) return;
  const float4* p = (const float4*)(in + (size_t)i * 8);
  float4 v0 = p[0], v1 = p[1];
  float vv[8] = {v0.x, v0.y, v0.z, v0.w, v1.x, v1.y, v1.z, v1.w};
  half8 hv;
#pragma unroll
  for (int j = 0; j < 8; ++j) hv[j] = (_Float16)vv[j];
  *(half8*)(h + (size_t)i * 8) = hv;
}

// W (K x Nc) fp32 -> transposed (Nc x K) f16
__global__ __launch_bounds__(256) void k_transT(const float* __restrict__ in,
                                                _Float16* __restrict__ hT,
                                                int K, int Nc) {
  __shared__ float t[32][33];
  const int tx = threadIdx.x & 31, ty = threadIdx.x >> 5;
  const int c0 = blockIdx.x * 32, k0 = blockIdx.y * 32;
#pragma unroll
  for (int r = 0; r < 4; ++r)
    t[ty + 8 * r][tx] = in[(size_t)(k0 + ty + 8 * r) * Nc + c0 + tx];
  __syncthreads();
#pragma unroll
  for (int r = 0; r < 4; ++r) {
    float v = t[tx][ty + 8 * r];
    int oc = c0 + ty + 8 * r;
    hT[(size_t)oc * K + k0 + tx] = (_Float16)v;
  }
}

// ============================================================
// CSR-by-dst construction (recomputed every call; no caching)
// ============================================================
__global__ void k_init_counts(int* cnt, int n) {
  int i = blockIdx.x * 256 + threadIdx.x;
  if (i < n) cnt[i] = 1;  // self-loop pre-counted
}

__global__ void k_count(const int* __restrict__ dst, int* cnt, int e) {
  int i = blockIdx.x * 256 + threadIdx.x;
  if (i < e) atomicAdd(&cnt[dst[i]], 1);
}

__global__ __launch_bounds__(1024) void k_scan(const int* __restrict__ cnt,
                                               int* __restrict__ rowstart,
                                               int* __restrict__ cursor, int n) {
  __shared__ int buf[1024];
  __shared__ int carry;
  int t = threadIdx.x;
  if (t == 0) carry = 0;
  __syncthreads();
  for (int base = 0; base < n; base += 1024) {
    int x = (base + t < n) ? cnt[base + t] : 0;
    buf[t] = x;
    __syncthreads();
    for (int off = 1; off < 1024; off <<= 1) {
      int v = (t >= off) ? buf[t - off] : 0;
      __syncthreads();
      buf[t] += v;
      __syncthreads();
    }
    int c0 = carry;
    int excl = buf[t] - x + c0;
    if (base + t < n) { rowstart[base + t] = excl; cursor[base + t] = excl; }
    __syncthreads();
    if (t == 0) carry = c0 + buf[1023];
    __syncthreads();
  }
  if (t == 0) rowstart[n] = carry;
}

__global__ void k_fill(const int* __restrict__ src, const int* __restrict__ dst,
                       int* cursor, int* __restrict__ col, int e) {
  int i = blockIdx.x * 256 + threadIdx.x;
  if (i < e) {
    int p = atomicAdd(&cursor[dst[i]], 1);
    col[p] = src[i];
  }
}

__global__ void k_fill_self(int* cursor, int* __restrict__ col, int n) {
  int i = blockIdx.x * 256 + threadIdx.x;
  if (i < n) {
    int p = atomicAdd(&cursor[i], 1);
    col[p] = i;
  }
}

// ============================================================
// per-node attention logits (f16 h): one wave per head
// ============================================================
__global__ __launch_bounds__(256) void k_alpha(
    const _Float16* __restrict__ h, const float* __restrict__ a_src,
    const float* __restrict__ a_dst, float* __restrict__ as_out,
    float* __restrict__ ad_out) {
  int n = blockIdx.x, t = threadIdx.x;
  const int wv = t >> 6, ln = t & 63;     // wave = head
  const int cb = wv * 256 + 4 * ln;
  half4v v = *(const half4v*)(h + (size_t)n * NPROJ + cb);
  float4 s4 = *(const float4*)(a_src + cb);
  float4 d4 = *(const float4*)(a_dst + cb);
  float vv[4] = {(float)v[0], (float)v[1], (float)v[2], (float)v[3]};
  float ss = vv[0] * s4.x + vv[1] * s4.y + vv[2] * s4.z + vv[3] * s4.w;
  float sd = vv[0] * d4.x + vv[1] * d4.y + vv[2] * d4.z + vv[3] * d4.w;
#pragma unroll
  for (int off = 32; off > 0; off >>= 1) {
    ss += __shfl_down(ss, off);
    sd += __shfl_down(sd, off);
  }
  if (ln == 0) {
    as_out[n * 4 + wv] = ss;
    ad_out[n * 4 + wv] = sd;
  }
}

// ============================================================
// fused segment-softmax + aggregation + bias/ELU/residual/LayerNorm
// BARRIER-FREE head decomposition: wave wv owns head wv's 256 cols.
// Softmax stats per head computed in-wave via shfl_xor; per-edge
// weights broadcast via shfl during gather (lane owns 4 cols, 8B load).
// Only the LayerNorm mean/var crosses waves (1 barrier).
// avg degree ~17 -> this removes ~25 syncthreads/node of the old form.
// ============================================================
__device__ __forceinline__ float lrelu02(float x) {
  return x > 0.f ? x : 0.2f * x;
}

__global__ __launch_bounds__(256) void k_aggregate_ln(
    const _Float16* __restrict__ h, const float* __restrict__ as_,
    const float* __restrict__ ad_, const int* __restrict__ rowstart,
    const int* __restrict__ col, const float* __restrict__ bias,
    const float* __restrict__ gamma, const float* __restrict__ beta,
    _Float16* __restrict__ xh, _Float16* __restrict__ xl) {
  __shared__ float sred[8];

  const int n = blockIdx.x, t = threadIdx.x;
  const int wv = t >> 6, l = t & 63;
  const int rs = rowstart[n], re = rowstart[n + 1];
  const float adn = ad_[n * 4 + wv];

  // pass 1: per-head max (in-wave)
  float mx = -1e30f;
  for (int e = rs + l; e < re; e += 64)
    mx = fmaxf(mx, lrelu02(as_[(size_t)col[e] * 4 + wv] + adn));
#pragma unroll
  for (int off = 32; off > 0; off >>= 1)
    mx = fmaxf(mx, __shfl_xor(mx, off));

  // pass 2: sum of exp (in-wave)
  float sm = 0.f;
  for (int e = rs + l; e < re; e += 64)
    sm += expf(lrelu02(as_[(size_t)col[e] * 4 + wv] + adn) - mx);
#pragma unroll
  for (int off = 32; off > 0; off >>= 1)
    sm += __shfl_xor(sm, off);
  const float Sinv = 1.f / (sm + 1e-16f);

  // pass 3: gather; lane owns cols wv*256 + 4l .. +3
  const int cb = wv * 256 + 4 * l;
  float acc[4] = {0.f, 0.f, 0.f, 0.f};
  for (int c0 = rs; c0 < re; c0 += 64) {
    const int idx = c0 + l;
    float w_l = 0.f;
    int s_l = 0;
    if (idx < re) {
      s_l = col[idx];
      w_l = expf(lrelu02(as_[(size_t)s_l * 4 + wv] + adn) - mx) * Sinv;
    }
    const int cnt = min(64, re - c0);
    for (int e = 0; e < cnt; ++e) {
      const float w = __shfl(w_l, e);
      const int s = __shfl(s_l, e);
      half4v hv = *(const half4v*)(h + (size_t)s * NPROJ + cb);
      acc[0] = fmaf(w, (float)hv[0], acc[0]);
      acc[1] = fmaf(w, (float)hv[1], acc[1]);
      acc[2] = fmaf(w, (float)hv[2], acc[2]);
      acc[3] = fmaf(w, (float)hv[3], acc[3]);
    }
  }

  // epilogue: bias, ELU, residual; LayerNorm stats
  const size_t base = (size_t)n * NPROJ + cb;
  float4 b4 = *(const float4*)(bias + cb);
  float bb[4] = {b4.x, b4.y, b4.z, b4.w};
  half4v xhv = *(const half4v*)(xh + base);
  half4v xlv = *(const half4v*)(xl + base);
  float v[4];
  float sum = 0.f, sumsq = 0.f;
#pragma unroll
  for (int j = 0; j < 4; ++j) {
    float u = acc[j] + bb[j];
    u = u > 0.f ? u : expm1f(u);
    u += (float)xhv[j] + (float)xlv[j];
    v[j] = u;
    sum += u;
    sumsq += u * u;
  }
#pragma unroll
  for (int off = 32; off > 0; off >>= 1) {
    sum += __shfl_xor(sum, off);
    sumsq += __shfl_xor(sumsq, off);
  }
  if (l == 0) {
    sred[wv] = sum;
    sred[4 + wv] = sumsq;
  }
  __syncthreads();
  const float tsum = sred[0] + sred[1] + sred[2] + sred[3];
  const float tssq = sred[4] + sred[5] + sred[6] + sred[7];
  const float mu = tsum * (1.f / 1024.f);
  const float var = tssq * (1.f / 1024.f) - mu * mu;
  const float rstd = rsqrtf(var + 1e-5f);

  float4 g4 = *(const float4*)(gamma + cb);
  float4 e4 = *(const float4*)(beta + cb);
  float gg[4] = {g4.x, g4.y, g4.z, g4.w};
  float ee[4] = {e4.x, e4.y, e4.z, e4.w};
  half4v oh, ol;
#pragma unroll
  for (int j = 0; j < 4; ++j) {
    float y = (v[j] - mu) * rstd * gg[j] + ee[j];
    _Float16 hh = (_Float16)y;
    oh[j] = hh;
    ol[j] = (_Float16)(y - (float)hh);
  }
  *(half4v*)(xh + base) = oh;
  *(half4v*)(xl + base) = ol;
}

// ============================================================
// pooling + classifier
// ============================================================
__global__ void k_scores(const float* __restrict__ tb,
                         const float* __restrict__ W2,
                         const float* __restrict__ b2,
                         float* __restrict__ scores, int N) {
  int n = blockIdx.x, lane = threadIdx.x;
  float s = 0.f;
  for (int k = lane; k < 512; k += 64) s = fmaf(tb[(size_t)n * 512 + k], W2[k], s);
  for (int off = 32; off > 0; off >>= 1) s += __shfl_down(s, off);
  if (lane == 0) scores[n] = s + b2[0];
}

__global__ void k_grange_init(int* gstart, int* gend, int N) {
  int g = threadIdx.x;
  if (g < NGRAPH) { gstart[g] = N; gend[g] = 0; }
}

__global__ void k_grange_mark(const int* __restrict__ batch, int* gstart,
                              int* gend, int N) {
  int n = blockIdx.x * 256 + threadIdx.x;
  if (n >= N) return;
  int b = batch[n];
  if (n == 0 || batch[n - 1] != b) gstart[b] = n;
  if (n == N - 1 || batch[n + 1] != b) gend[b] = n + 1;
}

__global__ __launch_bounds__(256) void k_pool(
    const float* __restrict__ scores, const _Float16* __restrict__ xh,
    const _Float16* __restrict__ xl, const int* __restrict__ gstart,
    const int* __restrict__ gend, float* __restrict__ pooled) {
  __shared__ float red[256];
  __shared__ float wt[256];
  __shared__ float m_s, s_s;
  int g = blockIdx.x, t = threadIdx.x;
  int rs = gstart[g], re = gend[g];

  float mx = -1e30f;
  for (int i = rs + t; i < re; i += 256) mx = fmaxf(mx, scores[i]);
  red[t] = mx;
  __syncthreads();
  for (int s = 128; s > 0; s >>= 1) {
    if (t < s) red[t] = fmaxf(red[t], red[t + s]);
    __syncthreads();
  }
  if (t == 0) m_s = red[0];
  __syncthreads();
  float m = m_s;

  float sm = 0.f;
  for (int i = rs + t; i < re; i += 256) sm += expf(scores[i] - m);
  red[t] = sm;
  __syncthreads();
  for (int s = 128; s > 0; s >>= 1) {
    if (t < s) red[t] += red[t + s];
    __syncthreads();
  }
  if (t == 0) s_s = red[0] + 1e-16f;
  __syncthreads();
  float sden = s_s;

  float acc[4] = {0.f, 0.f, 0.f, 0.f};
  for (int c0 = rs; c0 < re; c0 += 256) {
    int cnt = min(256, re - c0);
    if (t < cnt) wt[t] = expf(scores[c0 + t] - m) / sden;
    __syncthreads();
    for (int e = 0; e < cnt; ++e) {
      float w = wt[e];
      size_t base = (size_t)(c0 + e) * NPROJ + 4 * t;
      half4v hv = *(const half4v*)(xh + base);
      half4v lv = *(const half4v*)(xl + base);
#pragma unroll
      for (int j = 0; j < 4; ++j)
        acc[j] = fmaf(w, (float)hv[j] + (float)lv[j], acc[j]);
    }
    __syncthreads();
  }
#pragma unroll
  for (int j = 0; j < 4; ++j) pooled[(size_t)g * NPROJ + 4 * t + j] = acc[j];
}

__global__ __launch_bounds__(256) void k_cls1(const float* __restrict__ pooled,
                                              const float* __restrict__ W1,
                                              const float* __restrict__ b1,
                                              float* __restrict__ hid) {
  __shared__ float p[1024];
  int g = blockIdx.y;
  int colc = blockIdx.x * 256 + threadIdx.x;
  for (int k = threadIdx.x; k < 1024; k += 256) p[k] = pooled[(size_t)g * 1024 + k];
  __syncthreads();
  float s = 0.f;
  for (int k = 0; k < 1024; ++k) s = fmaf(p[k], W1[(size_t)k * 512 + colc], s);
  s += b1[colc];
  s = 0.5f * s * (1.f + erff(s * 0.70710678118654752f));
  hid[(size_t)g * 512 + colc] = s;
}

__global__ void k_cls2(const float* __restrict__ hid,
                       const float* __restrict__ W2,
                       const float* __restrict__ b2, float* __restrict__ out) {
  int o = blockIdx.x, g = blockIdx.y, lane = threadIdx.x;
  float s = 0.f;
  for (int k = lane; k < 512; k += 64) s = fmaf(hid[(size_t)g * 512 + k], W2[k * 14 + o], s);
  for (int off = 32; off > 0; off >>= 1) s += __shfl_down(s, off);
  if (lane == 0) out[g * 14 + o] = s + b2[o];
}

// ============================================================
extern "C" void kernel_launch(void* const* d_in, const int* in_sizes, int n_in,
                              void* d_out, int out_size, void* d_ws, size_t ws_size,
                              hipStream_t stream) {
  const float* x_in   = (const float*)d_in[0];
  const int*   eidx   = (const int*)d_in[1];
  const int*   batch  = (const int*)d_in[2];
  const float* proj_W = (const float*)d_in[3];
  const float* proj_b = (const float*)d_in[4];
  const float* gat_W  = (const float*)d_in[5];
  const float* a_src  = (const float*)d_in[6];
  const float* a_dst  = (const float*)d_in[7];
  const float* gat_b  = (const float*)d_in[8];
  const float* gamma  = (const float*)d_in[9];
  const float* beta   = (const float*)d_in[10];
  const float* pW1    = (const float*)d_in[11];
  const float* pb1    = (const float*)d_in[12];
  const float* pW2    = (const float*)d_in[13];
  const float* pb2    = (const float*)d_in[14];
  const float* cW1    = (const float*)d_in[15];
  const float* cb1    = (const float*)d_in[16];
  const float* cW2    = (const float*)d_in[17];
  const float* cb2    = (const float*)d_in[18];
  float* out = (float*)d_out;

  const int N = in_sizes[0] / NPROJ;  // 10000
  const int E = in_sizes[1] / 2;      // 160000
  const int Etot = E + N;

  char* ws = (char*)d_ws;
  size_t off = 0;
  auto alloc = [&](size_t bytes) -> void* {
    void* p = ws + off;
    off = (off + bytes + 255) & ~(size_t)255;
    return p;
  };
  _Float16* xh   = (_Float16*)alloc((size_t)N * NPROJ * 2);
  _Float16* xl   = (_Float16*)alloc((size_t)N * NPROJ * 2);
  _Float16* hf   = (_Float16*)alloc((size_t)N * NPROJ * 2);   // f16 h
  float*    hb   = (float*)alloc((size_t)N * NPROJ * 4);      // in-f16 / tb
  _Float16* pjh  = (_Float16*)alloc((size_t)NPROJ * NPROJ * 2);
  _Float16* gwh  = (_Float16*)alloc((size_t)3 * NPROJ * NPROJ * 2);
  _Float16* pwh  = (_Float16*)alloc((size_t)512 * NPROJ * 2);
  float* asb     = (float*)alloc((size_t)N * 4 * 4);
  float* adb     = (float*)alloc((size_t)N * 4 * 4);
  int*   cnt     = (int*)alloc((size_t)N * 4);
  int*   rowst   = (int*)alloc((size_t)(N + 1) * 4);
  int*   cursor  = (int*)alloc((size_t)N * 4);
  int*   ccol    = (int*)alloc((size_t)Etot * 4);
  float* scores  = (float*)alloc((size_t)N * 4);
  int*   gstart  = (int*)alloc(NGRAPH * 4);
  int*   gend    = (int*)alloc(NGRAPH * 4);
  float* pooled  = (float*)alloc((size_t)NGRAPH * NPROJ * 4);
  float* hid     = (float*)alloc((size_t)NGRAPH * 512 * 4);

  const int* esrc = eidx;
  const int* edst = eidx + E;

  // ---- CSR by dst ----
  k_init_counts<<<(N + 255) / 256, 256, 0, stream>>>(cnt, N);
  k_count<<<(E + 255) / 256, 256, 0, stream>>>(edst, cnt, E);
  k_scan<<<1, 1024, 0, stream>>>(cnt, rowst, cursor, N);
  k_fill<<<(E + 255) / 256, 256, 0, stream>>>(esrc, edst, cursor, ccol, E);
  k_fill_self<<<(N + 255) / 256, 256, 0, stream>>>(cursor, ccol, N);

  // ---- weight transposes (f16 hi) ----
  k_transT<<<dim3(32, 32), 256, 0, stream>>>(proj_W, pjh, NPROJ, NPROJ);
  for (int i = 0; i < 3; ++i)
    k_transT<<<dim3(32, 32), 256, 0, stream>>>(gat_W + (size_t)i * NPROJ * NPROJ,
                                               gwh + (size_t)i * NPROJ * NPROJ,
                                               NPROJ, NPROJ);
  k_transT<<<dim3(16, 32), 256, 0, stream>>>(pW1, pwh, NPROJ, 512);

  // ---- input f16 (scratch inside hb) + projection ----
  _Float16* inh = (_Float16*)hb;
  k_tof16<<<((N * NPROJ / 8) + 255) / 256, 256, 0, stream>>>(x_in, inh,
                                                             N * NPROJ / 8);
  const int MB = (N + 127) / 128;       // 79
  const int mpad8 = (MB + 7) / 8;       // 10
  const dim3 grid8(8 * mpad8 * 8);      // Nc=1024: lgn=3
  const dim3 grid4(4 * mpad8 * 8);      // Nc=512:  lgn=2
  gemm_mfma<0, 1><<<grid8, 256, 0, stream>>>(
      inh, pjh, proj_b, nullptr, xh, xl, N, NPROJ, 3, mpad8);

  // ---- 3 GAT layers ----
  for (int i = 0; i < 3; ++i) {
    gemm_mfma<0, 2><<<grid8, 256, 0, stream>>>(
        xh, gwh + (size_t)i * NPROJ * NPROJ,
        nullptr, nullptr, hf, nullptr, N, NPROJ, 3, mpad8);
    k_alpha<<<N, 256, 0, stream>>>(hf, a_src + i * NPROJ, a_dst + i * NPROJ, asb, adb);
    k_aggregate_ln<<<N, 256, 0, stream>>>(hf, asb, adb, rowst, ccol,
                                          gat_b + i * NPROJ, gamma + i * NPROJ,
                                          beta + i * NPROJ, xh, xl);
  }

  // ---- attention pooling ----
  float* tb = hb;  // N x 512 f32
  gemm_mfma<1, 0><<<grid4, 256, 0, stream>>>(
      xh, pwh, pb1, tb, nullptr, nullptr, N, 512, 2, mpad8);
  k_scores<<<N, 64, 0, stream>>>(tb, pW2, pb2, scores, N);
  k_grange_init<<<1, 64, 0, stream>>>(gstart, gend, N);
  k_grange_mark<<<(N + 255) / 256, 256, 0, stream>>>(batch, gstart, gend, N);
  k_pool<<<NGRAPH, 256, 0, stream>>>(scores, xh, xl, gstart, gend, pooled);

  // ---- classifier ----
  k_cls1<<<dim3(2, NGRAPH), 256, 0, stream>>>(pooled, cW1, cb1, hid);
  k_cls2<<<dim3(14, NGRAPH), 64, 0, stream>>>(hid, cW2, cb2, out);
}